// Round 1
// baseline (269.102 us; speedup 1.0000x reference)
//
#include <hip/hip_runtime.h>
#include <hip/hip_bf16.h>

// LoKr: out = x @ kron(w1, a@b).T * S, factored into 3 small GEMMs.
// x: [8192, 4096] fp32 (4*2048 positions), w1: [8,8], a: [512,64], b: [64,512]
// out[p, oi*512+ok] = sum_r a[ok,r] * v[p,oi,r]
//   v[p,oi,r] = sum_ij (S*w1[oi,ij]) * t[p,ij,r]
//   t[p,ij,r] = sum_il x[p, ij*512+il] * b[r,il]

typedef __attribute__((ext_vector_type(4))) float f32x4;
typedef __attribute__((ext_vector_type(8))) short s16x8;

__device__ inline unsigned short f2bf(float f) {
    unsigned u = __float_as_uint(f);
    u += 0x7FFF + ((u >> 16) & 1);   // round-to-nearest-even
    return (unsigned short)(u >> 16);
}

// Precompute: b -> bf16 [64][512] (row=r, col=il), a -> bf16 [512][64]
// (row=ok, col=r), w1s = w1 * (1/64). All into d_ws (re-poisoned each call,
// so recomputed every launch).
__global__ void lokr_pre(const float* __restrict__ w1,
                         const float* __restrict__ a,
                         const float* __restrict__ b,
                         unsigned short* __restrict__ b_bf,
                         unsigned short* __restrict__ a_bf,
                         float* __restrict__ w1s) {
    int i = blockIdx.x * 256 + threadIdx.x;
    if (i < 32768) {
        b_bf[i] = f2bf(b[i]);
        a_bf[i] = f2bf(a[i]);
    }
    if (i < 64) w1s[i] = w1[i] * (1.0f / 64.0f);
}

__global__ __launch_bounds__(256) void lokr_main(
    const float* __restrict__ x,
    const unsigned short* __restrict__ b_bf,
    const unsigned short* __restrict__ a_bf,
    const float* __restrict__ w1s,
    float* __restrict__ out)
{
    __shared__ float w1_s[64];
    // v per wave: 16 rows (lp*8+oi) x 64 r, bf16; row stride 72 ushorts
    // (144 B) keeps ds_read_b128 16B-aligned and staggers banks across rows.
    __shared__ __attribute__((aligned(16))) unsigned short v_lds[4][16 * 72];

    const int tid = threadIdx.x;
    if (tid < 64) w1_s[tid] = w1s[tid];
    __syncthreads();

    const int wave = tid >> 6;
    const int lane = tid & 63;
    const int col  = lane & 15;   // MFMA: A row / B col / C col
    const int quad = lane >> 4;

    const long p0 = ((long)blockIdx.x * 4 + wave) * 2;  // 2 positions per wave

    // ---------- stage 1: t[16][64] = X_rows[16 x 512] @ b^T ----------
    // A[m][k]: m = lane&15 -> global row p0*8+m, k = quad*8+j within k-step
    // B[k][n]: n = lane&15 -> r = rt*16+n, k = il = quad*8+j
    f32x4 acc0 = {0.f,0.f,0.f,0.f}, acc1 = acc0, acc2 = acc0, acc3 = acc0;
    const float* xrow = x + (p0 * 8 + col) * 512 + quad * 8;
    const unsigned short* bbase = b_bf + col * 512 + quad * 8;

    #pragma unroll 4
    for (int ks = 0; ks < 16; ++ks) {
        const float* ap = xrow + ks * 32;
        float4 lo = *(const float4*)(ap);
        float4 hi = *(const float4*)(ap + 4);
        s16x8 af;
        af[0] = (short)f2bf(lo.x); af[1] = (short)f2bf(lo.y);
        af[2] = (short)f2bf(lo.z); af[3] = (short)f2bf(lo.w);
        af[4] = (short)f2bf(hi.x); af[5] = (short)f2bf(hi.y);
        af[6] = (short)f2bf(hi.z); af[7] = (short)f2bf(hi.w);
        const unsigned short* bp = bbase + ks * 32;
        s16x8 bf0 = *(const s16x8*)(bp);
        s16x8 bf1 = *(const s16x8*)(bp + 16 * 512);
        s16x8 bf2 = *(const s16x8*)(bp + 32 * 512);
        s16x8 bf3 = *(const s16x8*)(bp + 48 * 512);
        acc0 = __builtin_amdgcn_mfma_f32_16x16x32_bf16(af, bf0, acc0, 0, 0, 0);
        acc1 = __builtin_amdgcn_mfma_f32_16x16x32_bf16(af, bf1, acc1, 0, 0, 0);
        acc2 = __builtin_amdgcn_mfma_f32_16x16x32_bf16(af, bf2, acc2, 0, 0, 0);
        acc3 = __builtin_amdgcn_mfma_f32_16x16x32_bf16(af, bf3, acc3, 0, 0, 0);
    }

    // ---------- stage 2: v[lp][oi][r] = sum_ij (S*w1[oi][ij]) * t ----------
    // C layout: lane holds t[row=quad*4+reg][col], row = lp*8+ij.
    // quad pair (0,1) covers lp=0 (ij 0-3 / 4-7), pair (2,3) covers lp=1.
    // shfl_xor(16) exchanges the complementary 4 ij rows; quad&1 splits the
    // 8 oi outputs so the pair doesn't duplicate work/writes.
    {
        const int lp = quad >> 1;
        const int oi_base = (quad & 1) * 4;
        f32x4 accs[4] = {acc0, acc1, acc2, acc3};
        #pragma unroll
        for (int rt = 0; rt < 4; ++rt) {
            float own[4], oth[4], tij[8];
            own[0] = accs[rt][0]; own[1] = accs[rt][1];
            own[2] = accs[rt][2]; own[3] = accs[rt][3];
            #pragma unroll
            for (int j = 0; j < 4; ++j) oth[j] = __shfl_xor(own[j], 16);
            if ((quad & 1) == 0) {
                #pragma unroll
                for (int j = 0; j < 4; ++j) { tij[j] = own[j]; tij[4 + j] = oth[j]; }
            } else {
                #pragma unroll
                for (int j = 0; j < 4; ++j) { tij[j] = oth[j]; tij[4 + j] = own[j]; }
            }
            #pragma unroll
            for (int oo = 0; oo < 4; ++oo) {
                const int oi = oi_base + oo;
                float v = 0.f;
                #pragma unroll
                for (int j = 0; j < 8; ++j) v += w1_s[oi * 8 + j] * tij[j];
                v_lds[wave][(lp * 8 + oi) * 72 + rt * 16 + col] = f2bf(v);
            }
        }
    }
    __syncthreads();

    // ---------- stage 3: out_rows[16 x 512] = v[16 x 64] @ a^T ----------
    // A[m][k]: m = lane&15 -> row (lp*8+oi), k = r = krt*32 + quad*8 + j
    // B[k][n]: n = lane&15 -> ok = nt*16+n, k = r
    const unsigned short* vbase = &v_lds[wave][col * 72 + quad * 8];
    s16x8 va0 = *(const s16x8*)(vbase);
    s16x8 va1 = *(const s16x8*)(vbase + 32);

    const unsigned short* abase = a_bf + col * 64 + quad * 8;
    float* outp = out + p0 * 4096;

    #pragma unroll 4
    for (int nt = 0; nt < 32; ++nt) {
        const unsigned short* apn = abase + nt * (16 * 64);
        s16x8 vb0 = *(const s16x8*)(apn);
        s16x8 vb1 = *(const s16x8*)(apn + 32);
        f32x4 c = {0.f, 0.f, 0.f, 0.f};
        c = __builtin_amdgcn_mfma_f32_16x16x32_bf16(va0, vb0, c, 0, 0, 0);
        c = __builtin_amdgcn_mfma_f32_16x16x32_bf16(va1, vb1, c, 0, 0, 0);
        #pragma unroll
        for (int reg = 0; reg < 4; ++reg) {
            const int row = quad * 4 + reg;            // lp*8 + oi
            outp[(long)(row >> 3) * 4096 + (row & 7) * 512 + nt * 16 + col] = c[reg];
        }
    }
}

extern "C" void kernel_launch(void* const* d_in, const int* in_sizes, int n_in,
                              void* d_out, int out_size, void* d_ws, size_t ws_size,
                              hipStream_t stream) {
    const float* x  = (const float*)d_in[0];  // [4,2048,4096]
    const float* w1 = (const float*)d_in[1];  // [8,8]
    const float* a  = (const float*)d_in[2];  // [512,64]
    const float* b  = (const float*)d_in[3];  // [64,512]

    unsigned short* b_bf = (unsigned short*)d_ws;          // 64 KB
    unsigned short* a_bf = b_bf + 32768;                   // 64 KB
    float*          w1s  = (float*)(a_bf + 32768);         // 256 B

    lokr_pre<<<128, 256, 0, stream>>>(w1, a, b, b_bf, a_bf, w1s);
    lokr_main<<<1024, 256, 0, stream>>>(x, b_bf, a_bf, w1s, (float*)d_out);
}